// Round 1
// baseline (827.258 us; speedup 1.0000x reference)
//
#include <hip/hip_runtime.h>
#include <stdint.h>

#define B_ 2
#define S_ 2048
#define D_ 1024
#define H_ 16
#define BH_ 32
#define SCALE_ 0.125f
#define INVDECAY_ 1.1111111111111112f

typedef unsigned short u16;
typedef unsigned int u32;
typedef __attribute__((ext_vector_type(8))) __bf16 bf16x8;
typedef __attribute__((ext_vector_type(4))) float f32x4;

#define GLOAD16(g, l) __builtin_amdgcn_global_load_lds((const __attribute__((address_space(1))) void*)(g), (__attribute__((address_space(3))) void*)(l), 16, 0, 0)

__device__ __forceinline__ u16 f2bf(float f) {
    u32 u = __builtin_bit_cast(u32, f);
    u = u + 0x7fffu + ((u >> 16) & 1u);
    return (u16)(u >> 16);
}

// ---- convert q/k/v fp32 -> bf16, contiguous [3][B*S*D] ----
__global__ __launch_bounds__(256) void k_convert_x(const float* __restrict__ q, const float* __restrict__ k,
                                                   const float* __restrict__ v, u16* __restrict__ Xb) {
    const int tot = 3 * (B_ * S_ * D_ / 4);  // 3145728 float4s
    for (int idx = blockIdx.x * 256 + threadIdx.x; idx < tot; idx += gridDim.x * 256) {
        int m = idx >> 20;            // B*S*D/4 = 2^20
        int e = idx & 0xFFFFF;
        const float4* src = (const float4*)(m == 0 ? q : (m == 1 ? k : v));
        float4 f = src[e];
        ushort4 o;
        o.x = f2bf(f.x); o.y = f2bf(f.y); o.z = f2bf(f.z); o.w = f2bf(f.w);
        ((ushort4*)Xb)[idx] = o;
    }
}

// ---- transpose+convert weights: W[in][out] fp32 -> Wt[out][in] bf16 (Wq,Wk,Wv -> Wt[3], Wo -> Wot) ----
__global__ __launch_bounds__(256) void k_convert_w(const float* __restrict__ Wq, const float* __restrict__ Wk,
                                                   const float* __restrict__ Wv, const float* __restrict__ Wo,
                                                   u16* __restrict__ Wt, u16* __restrict__ Wot) {
    __shared__ float tile[32][33];
    int bx = blockIdx.x;              // 4096 = 4 mats * 32 * 32 tiles
    int mat = bx >> 10;
    int tt = bx & 1023;
    int ti = (tt >> 5) * 32;          // in-dim base
    int tj = (tt & 31) * 32;          // out-dim base
    const float* W = mat == 0 ? Wq : mat == 1 ? Wk : mat == 2 ? Wv : Wo;
    u16* dst = (mat < 3) ? (Wt + (size_t)mat * 1024 * 1024) : Wot;
    for (int i = 0; i < 4; i++) {
        int e = i * 256 + threadIdx.x;
        int r = e >> 5, c = e & 31;
        tile[r][c] = W[(size_t)(ti + r) * 1024 + tj + c];
    }
    __syncthreads();
    for (int i = 0; i < 4; i++) {
        int e = i * 256 + threadIdx.x;
        int r = e >> 5, c = e & 31;   // r: out offset, c: in offset
        dst[(size_t)(tj + r) * 1024 + ti + c] = f2bf(tile[c][r]);
    }
}

// ---- QKV projection GEMM: [4096,1024] @ Wt^T -> head-major bf16 [bh][s][64] ----
__global__ __launch_bounds__(256) void k_gemm_qkv(const u16* __restrict__ Xb, const u16* __restrict__ Wt,
                                                  const float* __restrict__ bq, const float* __restrict__ bk,
                                                  const float* __restrict__ bv,
                                                  u16* __restrict__ Qb, u16* __restrict__ Kb, u16* __restrict__ Vb) {
    __shared__ __align__(16) u16 As[128 * 32];
    __shared__ __align__(16) u16 Bs[128 * 32];
    int bx = blockIdx.x;              // 768
    bx = (bx & 7) * 96 + (bx >> 3);   // XCD swizzle (768 % 8 == 0)
    const int mat = bx / 256;
    const int r = bx % 256;
    const int bm = (r & 31) * 128;
    const int bn = (r >> 5) * 128;
    const u16* A = Xb + (size_t)mat * (B_ * S_ * D_);
    const u16* Bt = Wt + (size_t)mat * (1024 * 1024);
    const int t = threadIdx.x, l = t & 63, w = t >> 6, ln = l & 15, hi = l >> 4;
    const int wm = (w >> 1) * 64, wn = (w & 1) * 64;
    f32x4 acc[4][4] = {};
    for (int kk = 0; kk < 1024; kk += 32) {
        __syncthreads();
        for (int c = 0; c < 2; c++) {
            int o = c * 4096 + w * 1024 + l * 16;
            int row = o >> 6, kb = (o & 63) >> 1;
            GLOAD16(A + (size_t)(bm + row) * 1024 + kk + kb, (char*)As + o);
            GLOAD16(Bt + (size_t)(bn + row) * 1024 + kk + kb, (char*)Bs + o);
        }
        __syncthreads();
        bf16x8 af[4], bfr[4];
        for (int m = 0; m < 4; m++) af[m] = *(const bf16x8*)&As[(wm + m * 16 + ln) * 32 + hi * 8];
        for (int n = 0; n < 4; n++) bfr[n] = *(const bf16x8*)&Bs[(wn + n * 16 + ln) * 32 + hi * 8];
        for (int m = 0; m < 4; m++)
            for (int n = 0; n < 4; n++)
                acc[m][n] = __builtin_amdgcn_mfma_f32_16x16x32_bf16(af[m], bfr[n], acc[m][n], 0, 0, 0);
    }
    const float* bias = mat == 0 ? bq : mat == 1 ? bk : bv;
    u16* dst = mat == 0 ? Qb : mat == 1 ? Kb : Vb;
    for (int n = 0; n < 4; n++) {
        int col = bn + wn + n * 16 + ln;
        float bb = bias[col];
        int head = col >> 6, dk = col & 63;
        for (int m = 0; m < 4; m++)
            for (int rr = 0; rr < 4; rr++) {
                int row = bm + wm + m * 16 + hi * 4 + rr;
                int b = row >> 11, s = row & 2047;
                dst[(((size_t)(b * H_ + head) * S_ + s) << 6) + dk] = f2bf(acc[m][n][rr] + bb);
            }
    }
}

// ---- V [bh][s][64] -> Vt [bh][64][s] ----
__global__ __launch_bounds__(256) void k_transpose_v(const u16* __restrict__ Vb, u16* __restrict__ Vt) {
    __shared__ u16 tile[64][72];
    int bx = blockIdx.x;              // 32 bh * 32 s-tiles
    int bh = bx >> 5, s0 = (bx & 31) * 64;
    for (int i = 0; i < 16; i++) {
        int e = i * 256 + threadIdx.x;
        int r = e >> 6, c = e & 63;
        tile[r][c] = Vb[(((size_t)bh * S_ + s0 + r) << 6) + c];
    }
    __syncthreads();
    for (int i = 0; i < 16; i++) {
        int e = i * 256 + threadIdx.x;
        int d = e >> 6, s = e & 63;
        Vt[((size_t)bh * 64 + d) * S_ + s0 + s] = tile[s][d];
    }
}

// ---- pass 1: row sums of P = exp(qk*scale - |dti-dtj|/decay) -> rinv = 1/sum ----
__global__ __launch_bounds__(256) void k_attn_rowsum(const u16* __restrict__ Qb, const u16* __restrict__ Kb,
                                                     const float* __restrict__ td, float* __restrict__ rinv) {
    __shared__ __align__(16) u16 Ks[128 * 64];
    __shared__ float tdi[128], tdj[128];
    int bx = blockIdx.x;
    int lb = (bx & 7) * 64 + (bx >> 3);   // XCD swizzle (512/8)
    const int bh = lb >> 4, i0 = (lb & 15) * 128;
    const int b = bh >> 4;
    const int t = threadIdx.x, l = t & 63, w = t >> 6, ln = l & 15, hi = l >> 4;
    if (t < 128) tdi[t] = td[b * S_ + i0 + t];
    bf16x8 aq[2][2];
    for (int ifr = 0; ifr < 2; ifr++)
        for (int kc = 0; kc < 2; kc++)
            aq[ifr][kc] = *(const bf16x8*)&Qb[(((size_t)bh * S_ + i0 + w * 32 + ifr * 16 + ln) << 6) + kc * 32 + hi * 8];
    float rs[2][4] = {};
    for (int jc = 0; jc < 16; jc++) {
        const int j0 = jc * 128;
        __syncthreads();
        for (int c = 0; c < 4; c++) {
            int o = c * 4096 + w * 1024 + l * 16;
            int row = o >> 7, slot = (o >> 4) & 7;
            GLOAD16(Kb + (((size_t)bh * S_ + j0 + row) << 6) + ((slot ^ (row & 7)) << 3), (char*)Ks + o);
        }
        if (t < 128) tdj[t] = td[b * S_ + j0 + t];
        __syncthreads();
        for (int jf = 0; jf < 8; jf++) {
            const int jrow = jf * 16 + ln;
            const char* kbase = (const char*)Ks + jrow * 128;
            const int kswz = (jrow & 7) << 4;
            bf16x8 kb0 = *(const bf16x8*)(kbase + ((hi * 16) ^ kswz));
            bf16x8 kb1 = *(const bf16x8*)(kbase + ((64 + hi * 16) ^ kswz));
            float dj = tdj[jrow];
            for (int ifr = 0; ifr < 2; ifr++) {
                f32x4 sc = {0.f, 0.f, 0.f, 0.f};
                sc = __builtin_amdgcn_mfma_f32_16x16x32_bf16(aq[ifr][0], kb0, sc, 0, 0, 0);
                sc = __builtin_amdgcn_mfma_f32_16x16x32_bf16(aq[ifr][1], kb1, sc, 0, 0, 0);
                for (int rr = 0; rr < 4; rr++) {
                    float di = tdi[w * 32 + ifr * 16 + hi * 4 + rr];
                    rs[ifr][rr] += __expf(fmaf(sc[rr], SCALE_, -fabsf(di - dj) * INVDECAY_));
                }
            }
        }
    }
    for (int off = 1; off < 16; off <<= 1)
        for (int ifr = 0; ifr < 2; ifr++)
            for (int rr = 0; rr < 4; rr++)
                rs[ifr][rr] += __shfl_xor(rs[ifr][rr], off, 64);
    if (ln == 0)
        for (int ifr = 0; ifr < 2; ifr++)
            for (int rr = 0; rr < 4; rr++)
                rinv[(size_t)bh * S_ + i0 + w * 32 + ifr * 16 + hi * 4 + rr] = 1.0f / rs[ifr][rr];
}

// ---- pass 2: write attn (normalized), accumulate ctx = attn @ V ----
__global__ __launch_bounds__(256) void k_attn_out(const u16* __restrict__ Qb, const u16* __restrict__ Kb,
                                                  const u16* __restrict__ Vt, const float* __restrict__ td,
                                                  const float* __restrict__ rinv,
                                                  float* __restrict__ attn, u16* __restrict__ ctxb) {
    __shared__ __align__(16) u16 Ks[128 * 64];
    __shared__ __align__(16) u16 Vs[64 * 128];
    __shared__ __align__(16) u16 Ps[4][32 * 128];
    __shared__ float tdi[128], tdj[128];
    int bx = blockIdx.x;
    int lb = (bx & 7) * 64 + (bx >> 3);
    const int bh = lb >> 4, i0 = (lb & 15) * 128;
    const int b = bh >> 4, h = bh & 15;
    const int t = threadIdx.x, l = t & 63, w = t >> 6, ln = l & 15, hi = l >> 4;
    if (t < 128) tdi[t] = td[b * S_ + i0 + t];
    bf16x8 aq[2][2];
    for (int ifr = 0; ifr < 2; ifr++)
        for (int kc = 0; kc < 2; kc++)
            aq[ifr][kc] = *(const bf16x8*)&Qb[(((size_t)bh * S_ + i0 + w * 32 + ifr * 16 + ln) << 6) + kc * 32 + hi * 8];
    float ir[2][4];
    for (int ifr = 0; ifr < 2; ifr++)
        for (int rr = 0; rr < 4; rr++)
            ir[ifr][rr] = rinv[(size_t)bh * S_ + i0 + w * 32 + ifr * 16 + hi * 4 + rr];
    f32x4 cacc[2][4] = {};
    for (int jc = 0; jc < 16; jc++) {
        const int j0 = jc * 128;
        __syncthreads();
        for (int c = 0; c < 4; c++) {
            int o = c * 4096 + w * 1024 + l * 16;
            {
                int row = o >> 7, slot = (o >> 4) & 7;
                GLOAD16(Kb + (((size_t)bh * S_ + j0 + row) << 6) + ((slot ^ (row & 7)) << 3), (char*)Ks + o);
            }
            {
                int dv = o >> 8, slot = (o >> 4) & 15;
                GLOAD16(Vt + ((size_t)bh * 64 + dv) * S_ + j0 + ((slot ^ (dv & 15)) << 3), (char*)Vs + o);
            }
        }
        if (t < 128) tdj[t] = td[b * S_ + j0 + t];
        __syncthreads();
        for (int jf = 0; jf < 8; jf++) {
            const int jrow = jf * 16 + ln;
            const char* kbase = (const char*)Ks + jrow * 128;
            const int kswz = (jrow & 7) << 4;
            bf16x8 kb0 = *(const bf16x8*)(kbase + ((hi * 16) ^ kswz));
            bf16x8 kb1 = *(const bf16x8*)(kbase + ((64 + hi * 16) ^ kswz));
            float dj = tdj[jrow];
            for (int ifr = 0; ifr < 2; ifr++) {
                f32x4 sc = {0.f, 0.f, 0.f, 0.f};
                sc = __builtin_amdgcn_mfma_f32_16x16x32_bf16(aq[ifr][0], kb0, sc, 0, 0, 0);
                sc = __builtin_amdgcn_mfma_f32_16x16x32_bf16(aq[ifr][1], kb1, sc, 0, 0, 0);
                for (int rr = 0; rr < 4; rr++) {
                    int prow = ifr * 16 + hi * 4 + rr;
                    float di = tdi[w * 32 + prow];
                    float p = __expf(fmaf(sc[rr], SCALE_, -fabsf(di - dj) * INVDECAY_));
                    __builtin_nontemporal_store(p * ir[ifr][rr],
                        attn + ((size_t)bh * S_ + i0 + w * 32 + prow) * S_ + j0 + jf * 16 + ln);
                    *(u16*)((char*)Ps[w] + prow * 256 + (((jf * 16 + ln) * 2) ^ ((prow & 15) << 4))) = f2bf(p);
                }
            }
        }
        for (int kc = 0; kc < 4; kc++) {
            bf16x8 ap[2];
            for (int ifr = 0; ifr < 2; ifr++) {
                int prow = ifr * 16 + ln;
                ap[ifr] = *(const bf16x8*)((char*)Ps[w] + prow * 256 + ((kc * 64 + hi * 16) ^ ((prow & 15) << 4)));
            }
            for (int dvb = 0; dvb < 4; dvb++) {
                int dvr = dvb * 16 + ln;
                bf16x8 bvf = *(const bf16x8*)((char*)Vs + dvr * 256 + ((kc * 64 + hi * 16) ^ ((dvr & 15) << 4)));
                for (int ifr = 0; ifr < 2; ifr++)
                    cacc[ifr][dvb] = __builtin_amdgcn_mfma_f32_16x16x32_bf16(ap[ifr], bvf, cacc[ifr][dvb], 0, 0, 0);
            }
        }
    }
    for (int ifr = 0; ifr < 2; ifr++)
        for (int dvb = 0; dvb < 4; dvb++)
            for (int rr = 0; rr < 4; rr++) {
                int i = i0 + w * 32 + ifr * 16 + hi * 4 + rr;
                ctxb[((size_t)b * S_ + i) * 1024 + h * 64 + dvb * 16 + ln] = f2bf(cacc[ifr][dvb][rr] * ir[ifr][rr]);
            }
}

// ---- out = ctx @ Wo + bo ----
__global__ __launch_bounds__(256) void k_gemm_out(const u16* __restrict__ ctxb, const u16* __restrict__ Wot,
                                                  const float* __restrict__ bo, float* __restrict__ out) {
    __shared__ __align__(16) u16 As[128 * 32];
    __shared__ __align__(16) u16 Bs[128 * 32];
    int bx = blockIdx.x;              // 256
    bx = (bx & 7) * 32 + (bx >> 3);
    const int bm = (bx & 31) * 128;
    const int bn = (bx >> 5) * 128;
    const int t = threadIdx.x, l = t & 63, w = t >> 6, ln = l & 15, hi = l >> 4;
    const int wm = (w >> 1) * 64, wn = (w & 1) * 64;
    f32x4 acc[4][4] = {};
    for (int kk = 0; kk < 1024; kk += 32) {
        __syncthreads();
        for (int c = 0; c < 2; c++) {
            int o = c * 4096 + w * 1024 + l * 16;
            int row = o >> 6, kb = (o & 63) >> 1;
            GLOAD16(ctxb + (size_t)(bm + row) * 1024 + kk + kb, (char*)As + o);
            GLOAD16(Wot + (size_t)(bn + row) * 1024 + kk + kb, (char*)Bs + o);
        }
        __syncthreads();
        bf16x8 af[4], bfr[4];
        for (int m = 0; m < 4; m++) af[m] = *(const bf16x8*)&As[(wm + m * 16 + ln) * 32 + hi * 8];
        for (int n = 0; n < 4; n++) bfr[n] = *(const bf16x8*)&Bs[(wn + n * 16 + ln) * 32 + hi * 8];
        for (int m = 0; m < 4; m++)
            for (int n = 0; n < 4; n++)
                acc[m][n] = __builtin_amdgcn_mfma_f32_16x16x32_bf16(af[m], bfr[n], acc[m][n], 0, 0, 0);
    }
    for (int n = 0; n < 4; n++) {
        int col = bn + wn + n * 16 + ln;
        float bb = bo[col];
        for (int m = 0; m < 4; m++)
            for (int rr = 0; rr < 4; rr++) {
                int row = bm + wm + m * 16 + hi * 4 + rr;
                out[(size_t)row * 1024 + col] = acc[m][n][rr] + bb;
            }
    }
}

extern "C" void kernel_launch(void* const* d_in, const int* in_sizes, int n_in,
                              void* d_out, int out_size, void* d_ws, size_t ws_size,
                              hipStream_t stream) {
    const float* q  = (const float*)d_in[0];
    const float* k  = (const float*)d_in[1];
    const float* v  = (const float*)d_in[2];
    const float* td = (const float*)d_in[3];
    const float* Wq = (const float*)d_in[4];
    const float* bq = (const float*)d_in[5];
    const float* Wk = (const float*)d_in[6];
    const float* bk = (const float*)d_in[7];
    const float* Wv = (const float*)d_in[8];
    const float* bv = (const float*)d_in[9];
    const float* Wo = (const float*)d_in[10];
    const float* bo = (const float*)d_in[11];
    // Wc1/bc1/Wc2/bc2 (d_in[12..15]) cancel in the softmax -> unused.

    char* p = (char*)d_ws;
    u16*   Xb   = (u16*)p;                 p += (size_t)3 * B_ * S_ * D_ * 2;   // 25165824
    u16*   Wt   = (u16*)p;                 p += (size_t)3 * 1024 * 1024 * 2;    // 6291456
    u16*   Wot  = (u16*)p;                 p += (size_t)1024 * 1024 * 2;        // 2097152
    u16*   Qb   = (u16*)p;                 p += (size_t)BH_ * S_ * 64 * 2;      // 8388608
    u16*   Kb   = (u16*)p;                 p += (size_t)BH_ * S_ * 64 * 2;
    u16*   Vb   = (u16*)p;                 p += (size_t)BH_ * S_ * 64 * 2;
    u16*   Vt   = (u16*)p;                 p += (size_t)BH_ * S_ * 64 * 2;
    u16*   ctxb = (u16*)p;                 p += (size_t)B_ * S_ * 1024 * 2;     // 8388608
    float* rinv = (float*)p;               p += (size_t)BH_ * S_ * 4;           // 262144

    float* out  = (float*)d_out;
    float* attn = out + (size_t)B_ * S_ * D_;   // 4194304 floats for `out`, then attn

    k_convert_x<<<3072, 256, 0, stream>>>(q, k, v, Xb);
    k_convert_w<<<4096, 256, 0, stream>>>(Wq, Wk, Wv, Wo, Wt, Wot);
    k_gemm_qkv<<<768, 256, 0, stream>>>(Xb, Wt, bq, bk, bv, Qb, Kb, Vb);
    k_transpose_v<<<1024, 256, 0, stream>>>(Vb, Vt);
    k_attn_rowsum<<<512, 256, 0, stream>>>(Qb, Kb, td, rinv);
    k_attn_out<<<512, 256, 0, stream>>>(Qb, Kb, Vt, td, rinv, attn, ctxb);
    k_gemm_out<<<256, 256, 0, stream>>>(ctxb, Wot, bo, out);
}